// Round 10
// baseline (664.766 us; speedup 1.0000x reference)
//
#include <hip/hip_runtime.h>

#define Bc 32
#define Kc 64
#define Wc 100
#define Hc 150
#define H3c 450
#define KWc 6400
#define ALPHAc 0.2f
#define THRESc 0.0002f

typedef unsigned int u32;
typedef unsigned short u16;
typedef __attribute__((ext_vector_type(8))) short short8;   // 8 bf16
typedef __attribute__((ext_vector_type(4))) float floatx4;  // 4 f32 acc

// ---- ws layout (float offsets), 4.55 MB ----
#define OFF_WX      0u          // 204800  Wx (B,K,W) fp32
#define OFF_CS      204800u     // 2048    causesum (B,K)
#define OFF_GX      206848u     // 921600  gl proj (s,b,g)
#define OFF_HT      1128448u    // 4800    h_t (B,H)
#define OFF_Z       1133248u    // 4800    z (B,H)

__device__ __forceinline__ float us2f(u16 u){ u32 x=((u32)u)<<16; return __uint_as_float(x); }
__device__ __forceinline__ u16 f2us(float f){
  u32 x = __float_as_uint(f);
  u32 r = (x + 0x7fffu + ((x>>16)&1u)) >> 16;   // RNE bf16
  return (u16)r;
}

// ---------- Wx = x @ lin_w.T + lin_b ----------
__global__ void wx_kernel(const float* __restrict__ x, const float* __restrict__ lin_w,
                          const float* __restrict__ lin_b, float* __restrict__ ws){
  int o = blockIdx.x*256 + threadIdx.x;
  if (o >= Bc*KWc) return;
  int i = o % Wc;
  int bk = o / Wc;
  const float4* xr = (const float4*)(x + bk*Wc);
  const float4* wr = (const float4*)(lin_w + i*Wc);
  float acc = lin_b[i];
  #pragma unroll
  for (int j=0;j<25;j++){
    float4 xv = xr[j], wv = wr[j];
    acc += xv.x*wv.x + xv.y*wv.y + xv.z*wv.z + xv.w*wv.w;
  }
  ws[OFF_WX + o] = acc;
}

// ---------- attention softmax + thresholded sum ----------
__global__ void attn_kernel(const float* __restrict__ y, const float* __restrict__ a,
                            const float* __restrict__ bias, float* __restrict__ ws){
  __shared__ float e_l[KWc];
  __shared__ float red[4];
  int row = blockIdx.x;          // b*64 + k
  int b = row >> 6, k = row & 63;
  int tid = threadIdx.x;
  float a0 = a[0], a1 = a[1];
  float yv = y[row];
  const float* v = ws + OFF_WX + b*KWc;
  const float* br = bias + k*KWc;
  float m = -3.4e38f;
  for (int j=tid; j<KWc; j+=256){
    float e = a0*yv + a1*v[j] + br[j];
    e = (e >= 0.f) ? e : ALPHAc*e;
    e_l[j] = e;
    m = fmaxf(m, e);
  }
  for (int o=32;o;o>>=1) m = fmaxf(m, __shfl_down(m, o));
  if ((tid&63)==0) red[tid>>6] = m;
  __syncthreads();
  m = fmaxf(fmaxf(red[0],red[1]), fmaxf(red[2],red[3]));
  __syncthreads();
  float ssum = 0.f;
  for (int j=tid; j<KWc; j+=256){
    float ex = expf(e_l[j]-m);
    e_l[j] = ex;
    ssum += ex;
  }
  for (int o=32;o;o>>=1) ssum += __shfl_down(ssum, o);
  if ((tid&63)==0) red[tid>>6] = ssum;
  __syncthreads();
  float s = red[0]+red[1]+red[2]+red[3];
  __syncthreads();
  float cs = 0.f;
  for (int j=tid; j<KWc; j+=256){
    float att = e_l[j] / s;
    if (att >= THRESc) cs += v[j];
  }
  for (int o=32;o;o>>=1) cs += __shfl_down(cs, o);
  if ((tid&63)==0) red[tid>>6] = cs;
  __syncthreads();
  if (tid==0) ws[OFF_CS + row] = red[0]+red[1]+red[2]+red[3];
}

// ---------- gl input projection ----------
__global__ void glproj_kernel(const float* __restrict__ gl_wih, const float* __restrict__ gl_bih,
                              float* __restrict__ ws){
  int o = blockIdx.x*256 + threadIdx.x;
  if (o >= Kc*Bc*H3c) return;
  int g = o % H3c;
  int t = o / H3c;               // s*32 + b
  int b = t & 31, s = t >> 5;
  float cs = ws[OFF_CS + b*Kc + s];
  const float4* xr = (const float4*)(ws + OFF_WX + b*KWc + s*Wc);
  const float4* wr = (const float4*)(gl_wih + g*Wc);
  float acc = gl_bih[g];
  #pragma unroll
  for (int j=0;j<25;j++){
    float4 wv = wr[j], xv = xr[j];
    acc += (xv.x+cs)*wv.x + (xv.y+cs)*wv.y + (xv.z+cs)*wv.z + (xv.w+cs)*wv.w;
  }
  ws[OFF_GX + o] = acc;
}

// ---------- gl recurrent GRU v5 (R8-passing): MFMA, 4 blocks x 8 batches ----------
__global__ void __launch_bounds__(512,1) glgru4_kernel(
    const float* __restrict__ gl_whh, const float* __restrict__ gl_bhh,
    float* __restrict__ ws){
  __shared__ __align__(16) u16 bF[10*16*40];   // [chunk][n=16(8 used)][k-row stride 40]
  __shared__ float g_l[480*10];                // gate rows x 8 batches, stride 10
  int b0 = blockIdx.x*8;
  int tid = threadIdx.x;
  int w = tid >> 6, lane = tid & 63, quad = lane >> 4, n16 = lane & 15;

  // ---- resident A-fragments: A[m=lane&15][k=quad*8+j], bf16 ----
  short8 whhA[4][5];
  #pragma unroll
  for (int ti=0; ti<4; ti++){
    int tile = w*4 + ti;                 // 0..31 (30,31 dummy)
    int sec = tile/10;                   // 0=r,1=z,2=n
    int sr = (tile - sec*10)*16 + n16;   // row within 160-padded section
    bool rowok = (tile < 30) && (sr < Hc);
    int grow = sec*Hc + sr;
    #pragma unroll
    for (int c=0;c<5;c++){
      union { short8 v; u16 u[8]; } t8;
      #pragma unroll
      for (int j=0;j<8;j++){
        int k = c*32 + quad*8 + j;
        float v = (rowok && k < Hc) ? gl_whh[(size_t)grow*Hc + k] : 0.f;
        t8.u[j] = f2us(v);
      }
      whhA[ti][c] = t8.v;
    }
  }
  // zero B staging (pads stay zero; h0 = 0)
  for (int i=tid; i<10*16*40/2; i+=512) ((u32*)bF)[i] = 0u;

  // ---- per-task state: 1200 tasks, <=3/thread, bl = tau/150, t = tau%150 ----
  float hst[3] = {0.f,0.f,0.f};
  float bh_r[3], bh_z[3], bh_n[3];
  int tT[3], tBL[3];
  #pragma unroll
  for (int q=0;q<3;q++){
    int task = tid + q*512;
    if (task < 1200){
      int bl = task/150, t = task - bl*150;
      tT[q] = t; tBL[q] = bl;
      bh_r[q] = gl_bhh[t];
      bh_z[q] = gl_bhh[Hc+t];
      bh_n[q] = gl_bhh[2*Hc+t];
    } else { tT[q] = 0; tBL[q] = -1; }
  }

  for (int s=0;s<Kc;s++){
    __syncthreads();   // bF ready
    // prefetch gx, coalesced in t (overlaps MFMA)
    float gxr[3], gxz[3], gxn[3];
    const float* gxb = ws + OFF_GX + (size_t)(s*Bc)*H3c;
    #pragma unroll
    for (int q=0;q<3;q++){
      if (tBL[q] >= 0){
        const float* gp = gxb + (size_t)(b0+tBL[q])*H3c;
        int t = tT[q];
        gxr[q] = gp[t]; gxz[q] = gp[Hc+t]; gxn[q] = gp[2*Hc+t];
      }
    }
    // MFMA stage
    floatx4 acc[4] = {{0.f,0.f,0.f,0.f},{0.f,0.f,0.f,0.f},{0.f,0.f,0.f,0.f},{0.f,0.f,0.f,0.f}};
    const u16* bBase = bF + (size_t)n16*40 + (size_t)quad*8;
    #pragma unroll
    for (int c=0;c<10;c++){
      short8 b8 = *(const short8*)(bBase + (size_t)c*640);
      int ca = (c<5)? c : (c-5);
      #pragma unroll
      for (int ti=0;ti<4;ti++)
        acc[ti] = __builtin_amdgcn_mfma_f32_16x16x32_bf16(whhA[ti][ca], b8, acc[ti], 0,0,0);
    }
    // C -> LDS (C layout: col=lane&15, row=quad*4+reg); only 8 batches used
    if (n16 < 8){
      #pragma unroll
      for (int ti=0;ti<4;ti++){
        int tile = w*4 + ti;
        if (tile < 30){
          int row0 = tile*16 + quad*4;
          float* gp = g_l + row0*10 + n16;
          #pragma unroll
          for (int r=0;r<4;r++) gp[r*10] = acc[ti][r];
        }
      }
    }
    __syncthreads();   // gates ready; bF MFMA reads done
    #pragma unroll
    for (int q=0;q<3;q++){
      if (tBL[q] >= 0){
        int t = tT[q], bl = tBL[q];
        float a_r = gxr[q] + g_l[t*10+bl] + bh_r[q];
        float a_z = gxz[q] + g_l[(160+t)*10+bl] + bh_z[q];
        float r  = 1.f/(1.f+__expf(-a_r));
        float zz = 1.f/(1.f+__expf(-a_z));
        float nx = gxn[q] + r*(g_l[(320+t)*10+bl] + bh_n[q]);
        nx = fminf(fmaxf(nx,-15.f),15.f);
        float e2 = __expf(2.f*nx);
        float n = (e2-1.f)/(e2+1.f);
        float h = (1.f-zz)*n + zz*hst[q];
        hst[q] = h;
        u16 hi = f2us(h); float hif = us2f(hi); u16 lo = f2us(h - hif);
        bF[(t>>5)*640 + bl*40 + (t&31)] = hi;
        bF[(5+(t>>5))*640 + bl*40 + (t&31)] = lo;
      }
    }
  }
  #pragma unroll
  for (int q=0;q<3;q++){
    if (tBL[q] >= 0)
      ws[OFF_HT + (size_t)(b0+tBL[q])*Hc + tT[q]] = hst[q];
  }
}

// ---------- z = mu + sigma * z_noise ----------
__global__ void z_kernel(const float* __restrict__ z_noise, const float* __restrict__ mu_w,
                         const float* __restrict__ mu_b, const float* __restrict__ std_w,
                         const float* __restrict__ std_b, float* __restrict__ ws){
  int o = blockIdx.x*256 + threadIdx.x;
  if (o >= Bc*Hc) return;
  int t = o % Hc, b = o / Hc;
  const float* h = ws + OFF_HT + b*Hc;
  const float2* mwr = (const float2*)(mu_w + t*Hc);
  const float2* swr = (const float2*)(std_w + t*Hc);
  float mu = mu_b[t], lv = std_b[t];
  for (int j=0;j<Hc/2;j++){
    float2 mw = mwr[j], sw = swr[j];
    float h0 = h[2*j], h1 = h[2*j+1];
    mu += h0*mw.x + h1*mw.y;
    lv += h0*sw.x + h1*sw.y;
  }
  float sg = expf(0.5f*lv);
  ws[OFF_Z + o] = mu + sg*z_noise[o];
}

// ---------- causes v5: R8 structure, batch groups 4x8 -> 8x4 (2 blocks/CU) ----------
// block = bg*64+kk, bg 0..7, 4 batches each; all 8 blocks of net kk on XCD kk%8.
__global__ void __launch_bounds__(512,2) causes3_kernel(
    const float* __restrict__ net_wih, const float* __restrict__ net_whh,
    const float* __restrict__ net_bih, const float* __restrict__ net_bhh,
    const float* __restrict__ ws, float* __restrict__ out){
  __shared__ __align__(16) u16 bF[14*16*40];   // [chunk][n=16(4 used)][k-row stride 40]
  __shared__ float g_rz[320*10];
  __shared__ float g_nh[160*10];
  __shared__ float g_np[160*10];
  int kk = blockIdx.x & 63, bg = blockIdx.x >> 6, b0 = bg*4;
  int tid = threadIdx.x;
  int w = tid >> 6, lane = tid & 63, quad = lane >> 4, n16 = lane & 15;
  const float* whhk = net_whh + (size_t)kk*H3c*Hc;
  const float* wihk = net_wih + (size_t)kk*H3c*Wc;
  const float* bihk = net_bih + kk*H3c;
  const float* bhhk = net_bhh + kk*H3c;

  short8 whhA[4][5], wihA[4][4];
  #pragma unroll
  for (int ti=0; ti<4; ti++){
    int tile = w*4 + ti;
    int sec = tile/10;
    int sr = (tile - sec*10)*16 + n16;
    bool rowok = (tile < 30) && (sr < Hc);
    int grow = sec*Hc + sr;
    #pragma unroll
    for (int c=0;c<5;c++){
      union { short8 v; u16 u[8]; } t8;
      #pragma unroll
      for (int j=0;j<8;j++){
        int k = c*32 + quad*8 + j;
        float v = (rowok && k < Hc) ? whhk[(size_t)grow*Hc + k] : 0.f;
        t8.u[j] = f2us(v);
      }
      whhA[ti][c] = t8.v;
    }
    #pragma unroll
    for (int c=0;c<4;c++){
      union { short8 v; u16 u[8]; } t8;
      #pragma unroll
      for (int j=0;j<8;j++){
        int k = c*32 + quad*8 + j;
        float v = (rowok && k < Wc) ? wihk[(size_t)grow*Wc + k] : 0.f;
        t8.u[j] = f2us(v);
      }
      wihA[ti][c] = t8.v;
    }
  }

  for (int i=tid; i<14*16*40/2; i+=512) ((u32*)bF)[i] = 0u;
  __syncthreads();

  // ---- 600 tasks (150 t x 4 batches), <=2/thread: t = task>>2, bb = task&3 ----
  float hst[2] = {0.f,0.f};
  float brz_r[2], brz_z[2], bnh_[2], bnp_[2];
  #pragma unroll
  for (int q=0;q<2;q++){
    int task = tid + q*512;
    if (task < 600){
      int t = task >> 2, bb = task & 3;
      float h = ws[OFF_Z + (b0+bb)*Hc + t];
      hst[q] = h;
      brz_r[q] = bhhk[t]      + bihk[t];
      brz_z[q] = bhhk[Hc+t]   + bihk[Hc+t];
      bnh_[q]  = bhhk[2*Hc+t];
      bnp_[q]  = bihk[2*Hc+t];
      u16 hi = f2us(h); float hif = us2f(hi); u16 lo = f2us(h - hif);
      bF[(t>>5)*640 + bb*40 + (t&31)] = hi;
      bF[(5+(t>>5))*640 + bb*40 + (t&31)] = lo;
    }
  }
  for (int it=tid; it<400; it+=512){
    int bb = it/100, i = it - bb*100;
    float xv = ws[OFF_WX + (b0+bb)*KWc + i];
    bF[(10+(i>>5))*640 + bb*40 + (i&31)] = f2us(xv);
  }

  const bool isN = (w >= 5);
  for (int s=0;s<Kc;s++){
    __syncthreads();
    floatx4 accH[4] = {{0.f,0.f,0.f,0.f},{0.f,0.f,0.f,0.f},{0.f,0.f,0.f,0.f},{0.f,0.f,0.f,0.f}};
    floatx4 accP[4] = {{0.f,0.f,0.f,0.f},{0.f,0.f,0.f,0.f},{0.f,0.f,0.f,0.f},{0.f,0.f,0.f,0.f}};
    const u16* bBase = bF + (size_t)n16*40 + (size_t)quad*8;
    short8 bcur = *(const short8*)bBase;
    #pragma unroll
    for (int c=0;c<14;c++){
      short8 bnext = bcur;
      if (c<13) bnext = *(const short8*)(bBase + (size_t)(c+1)*640);
      short8 b = bcur;
      if (c < 10){
        int ca = (c<5)? c : (c-5);
        #pragma unroll
        for (int ti=0;ti<4;ti++)
          accH[ti] = __builtin_amdgcn_mfma_f32_16x16x32_bf16(whhA[ti][ca], b, accH[ti], 0,0,0);
      } else {
        int ca = c-10;
        if (isN){
          #pragma unroll
          for (int ti=0;ti<4;ti++)
            accP[ti] = __builtin_amdgcn_mfma_f32_16x16x32_bf16(wihA[ti][ca], b, accP[ti], 0,0,0);
        } else {
          #pragma unroll
          for (int ti=0;ti<4;ti++)
            accH[ti] = __builtin_amdgcn_mfma_f32_16x16x32_bf16(wihA[ti][ca], b, accH[ti], 0,0,0);
        }
      }
      bcur = bnext;
    }
    if (n16 < 4){
      #pragma unroll
      for (int ti=0;ti<4;ti++){
        int tile = w*4 + ti;
        if (tile < 30){
          int sec = tile/10;
          int srb = (tile - sec*10)*16 + quad*4;
          if (sec < 2){
            float* gp = g_rz + (sec*160 + srb)*10 + n16;
            #pragma unroll
            for (int r=0;r<4;r++) gp[r*10] = accH[ti][r];
          } else {
            float* gh = g_nh + srb*10 + n16;
            float* gq = g_np + srb*10 + n16;
            #pragma unroll
            for (int r=0;r<4;r++){ gh[r*10] = accH[ti][r]; gq[r*10] = accP[ti][r]; }
          }
        }
      }
    }
    __syncthreads();
    #pragma unroll
    for (int q=0;q<2;q++){
      int task = tid + q*512;
      if (task < 600){
        int t = task >> 2, bb = task & 3;
        float a_r = g_rz[t*10+bb] + brz_r[q];
        float a_z = g_rz[(160+t)*10+bb] + brz_z[q];
        float r  = 1.f/(1.f+__expf(-a_r));
        float zz = 1.f/(1.f+__expf(-a_z));
        float nx = (g_np[t*10+bb] + bnp_[q]) + r*(g_nh[t*10+bb] + bnh_[q]);
        nx = fminf(fmaxf(nx,-15.f),15.f);
        float e2 = __expf(2.f*nx);
        float n = (e2-1.f)/(e2+1.f);
        float h = (1.f-zz)*n + zz*hst[q];
        hst[q] = h;
        u16 hi = f2us(h); float hif = us2f(hi); u16 lo = f2us(h - hif);
        bF[(t>>5)*640 + bb*40 + (t&31)] = hi;
        bF[(5+(t>>5))*640 + bb*40 + (t&31)] = lo;
      }
    }
    if (s < Kc-1){
      for (int it=tid; it<400; it+=512){
        int bb = it/100, i = it - bb*100;
        float xv = ws[OFF_WX + (b0+bb)*KWc + (s+1)*Wc + i];
        bF[(10+(i>>5))*640 + bb*40 + (i&31)] = f2us(xv);
      }
    }
  }
  #pragma unroll
  for (int q=0;q<2;q++){
    int task = tid + q*512;
    if (task < 600){
      int t = task >> 2, bb = task & 3;
      out[((size_t)(b0+bb)*Kc + kk)*Hc + t] = hst[q];
    }
  }
}

extern "C" void kernel_launch(void* const* d_in, const int* in_sizes, int n_in,
                              void* d_out, int out_size, void* d_ws, size_t ws_size,
                              hipStream_t stream){
  const float* x        = (const float*)d_in[0];
  const float* y        = (const float*)d_in[1];
  const float* z_noise  = (const float*)d_in[2];
  const float* lin_w    = (const float*)d_in[3];
  const float* lin_b    = (const float*)d_in[4];
  const float* a        = (const float*)d_in[5];
  const float* bias     = (const float*)d_in[6];
  const float* gl_wih   = (const float*)d_in[7];
  const float* gl_whh   = (const float*)d_in[8];
  const float* gl_bih   = (const float*)d_in[9];
  const float* gl_bhh   = (const float*)d_in[10];
  const float* mu_w     = (const float*)d_in[11];
  const float* mu_b     = (const float*)d_in[12];
  const float* std_w    = (const float*)d_in[13];
  const float* std_b    = (const float*)d_in[14];
  const float* net_wih  = (const float*)d_in[15];
  const float* net_whh  = (const float*)d_in[16];
  const float* net_bih  = (const float*)d_in[17];
  const float* net_bhh  = (const float*)d_in[18];
  float* ws = (float*)d_ws;
  float* out = (float*)d_out;

  wx_kernel<<<(Bc*KWc+255)/256, 256, 0, stream>>>(x, lin_w, lin_b, ws);
  attn_kernel<<<Bc*Kc, 256, 0, stream>>>(y, a, bias, ws);
  glproj_kernel<<<(Kc*Bc*H3c+255)/256, 256, 0, stream>>>(gl_wih, gl_bih, ws);
  glgru4_kernel<<<4, 512, 0, stream>>>(gl_whh, gl_bhh, ws);
  z_kernel<<<(Bc*Hc+255)/256, 256, 0, stream>>>(z_noise, mu_w, mu_b, std_w, std_b, ws);
  causes3_kernel<<<512, 512, 0, stream>>>(net_wih, net_whh, net_bih, net_bhh, ws, out);
}

// Round 11
// 548.868 us; speedup vs baseline: 1.2112x; 1.2112x over previous
//
#include <hip/hip_runtime.h>

#define Bc 32
#define Kc 64
#define Wc 100
#define Hc 150
#define H3c 450
#define KWc 6400
#define ALPHAc 0.2f
#define THRESc 0.0002f

typedef unsigned int u32;
typedef unsigned short u16;
typedef __attribute__((ext_vector_type(8))) short short8;   // 8 bf16
typedef __attribute__((ext_vector_type(4))) float floatx4;  // 4 f32 acc

// ---- ws layout (float offsets), 4.55 MB ----
#define OFF_WX      0u          // 204800  Wx (B,K,W) fp32
#define OFF_CS      204800u     // 2048    causesum (B,K)
#define OFF_GX      206848u     // 921600  gl proj (s,b,g)
#define OFF_HT      1128448u    // 4800    h_t (B,H)
#define OFF_Z       1133248u    // 4800    z (B,H)

__device__ __forceinline__ float us2f(u16 u){ u32 x=((u32)u)<<16; return __uint_as_float(x); }
__device__ __forceinline__ u16 f2us(float f){
  u32 x = __float_as_uint(f);
  u32 r = (x + 0x7fffu + ((x>>16)&1u)) >> 16;   // RNE bf16
  return (u16)r;
}

// ---------- Wx = x @ lin_w.T + lin_b ----------
__global__ void wx_kernel(const float* __restrict__ x, const float* __restrict__ lin_w,
                          const float* __restrict__ lin_b, float* __restrict__ ws){
  int o = blockIdx.x*256 + threadIdx.x;
  if (o >= Bc*KWc) return;
  int i = o % Wc;
  int bk = o / Wc;
  const float4* xr = (const float4*)(x + bk*Wc);
  const float4* wr = (const float4*)(lin_w + i*Wc);
  float acc = lin_b[i];
  #pragma unroll
  for (int j=0;j<25;j++){
    float4 xv = xr[j], wv = wr[j];
    acc += xv.x*wv.x + xv.y*wv.y + xv.z*wv.z + xv.w*wv.w;
  }
  ws[OFF_WX + o] = acc;
}

// ---------- attention softmax + thresholded sum ----------
__global__ void attn_kernel(const float* __restrict__ y, const float* __restrict__ a,
                            const float* __restrict__ bias, float* __restrict__ ws){
  __shared__ float e_l[KWc];
  __shared__ float red[4];
  int row = blockIdx.x;          // b*64 + k
  int b = row >> 6, k = row & 63;
  int tid = threadIdx.x;
  float a0 = a[0], a1 = a[1];
  float yv = y[row];
  const float* v = ws + OFF_WX + b*KWc;
  const float* br = bias + k*KWc;
  float m = -3.4e38f;
  for (int j=tid; j<KWc; j+=256){
    float e = a0*yv + a1*v[j] + br[j];
    e = (e >= 0.f) ? e : ALPHAc*e;
    e_l[j] = e;
    m = fmaxf(m, e);
  }
  for (int o=32;o;o>>=1) m = fmaxf(m, __shfl_down(m, o));
  if ((tid&63)==0) red[tid>>6] = m;
  __syncthreads();
  m = fmaxf(fmaxf(red[0],red[1]), fmaxf(red[2],red[3]));
  __syncthreads();
  float ssum = 0.f;
  for (int j=tid; j<KWc; j+=256){
    float ex = expf(e_l[j]-m);
    e_l[j] = ex;
    ssum += ex;
  }
  for (int o=32;o;o>>=1) ssum += __shfl_down(ssum, o);
  if ((tid&63)==0) red[tid>>6] = ssum;
  __syncthreads();
  float s = red[0]+red[1]+red[2]+red[3];
  __syncthreads();
  float cs = 0.f;
  for (int j=tid; j<KWc; j+=256){
    float att = e_l[j] / s;
    if (att >= THRESc) cs += v[j];
  }
  for (int o=32;o;o>>=1) cs += __shfl_down(cs, o);
  if ((tid&63)==0) red[tid>>6] = cs;
  __syncthreads();
  if (tid==0) ws[OFF_CS + row] = red[0]+red[1]+red[2]+red[3];
}

// ---------- gl input projection ----------
__global__ void glproj_kernel(const float* __restrict__ gl_wih, const float* __restrict__ gl_bih,
                              float* __restrict__ ws){
  int o = blockIdx.x*256 + threadIdx.x;
  if (o >= Kc*Bc*H3c) return;
  int g = o % H3c;
  int t = o / H3c;               // s*32 + b
  int b = t & 31, s = t >> 5;
  float cs = ws[OFF_CS + b*Kc + s];
  const float4* xr = (const float4*)(ws + OFF_WX + b*KWc + s*Wc);
  const float4* wr = (const float4*)(gl_wih + g*Wc);
  float acc = gl_bih[g];
  #pragma unroll
  for (int j=0;j<25;j++){
    float4 wv = wr[j], xv = xr[j];
    acc += (xv.x+cs)*wv.x + (xv.y+cs)*wv.y + (xv.z+cs)*wv.z + (xv.w+cs)*wv.w;
  }
  ws[OFF_GX + o] = acc;
}

// ---------- gl recurrent GRU v5 (R8-passing): MFMA, 4 blocks x 8 batches ----------
__global__ void __launch_bounds__(512,1) glgru4_kernel(
    const float* __restrict__ gl_whh, const float* __restrict__ gl_bhh,
    float* __restrict__ ws){
  __shared__ __align__(16) u16 bF[10*16*40];   // [chunk][n=16(8 used)][k-row stride 40]
  __shared__ float g_l[480*10];                // gate rows x 8 batches, stride 10
  int b0 = blockIdx.x*8;
  int tid = threadIdx.x;
  int w = tid >> 6, lane = tid & 63, quad = lane >> 4, n16 = lane & 15;

  short8 whhA[4][5];
  #pragma unroll
  for (int ti=0; ti<4; ti++){
    int tile = w*4 + ti;
    int sec = tile/10;
    int sr = (tile - sec*10)*16 + n16;
    bool rowok = (tile < 30) && (sr < Hc);
    int grow = sec*Hc + sr;
    #pragma unroll
    for (int c=0;c<5;c++){
      union { short8 v; u16 u[8]; } t8;
      #pragma unroll
      for (int j=0;j<8;j++){
        int k = c*32 + quad*8 + j;
        float v = (rowok && k < Hc) ? gl_whh[(size_t)grow*Hc + k] : 0.f;
        t8.u[j] = f2us(v);
      }
      whhA[ti][c] = t8.v;
    }
  }
  for (int i=tid; i<10*16*40/2; i+=512) ((u32*)bF)[i] = 0u;

  float hst[3] = {0.f,0.f,0.f};
  float bh_r[3], bh_z[3], bh_n[3];
  int tT[3], tBL[3];
  #pragma unroll
  for (int q=0;q<3;q++){
    int task = tid + q*512;
    if (task < 1200){
      int bl = task/150, t = task - bl*150;
      tT[q] = t; tBL[q] = bl;
      bh_r[q] = gl_bhh[t];
      bh_z[q] = gl_bhh[Hc+t];
      bh_n[q] = gl_bhh[2*Hc+t];
    } else { tT[q] = 0; tBL[q] = -1; }
  }

  for (int s=0;s<Kc;s++){
    __syncthreads();
    float gxr[3], gxz[3], gxn[3];
    const float* gxb = ws + OFF_GX + (size_t)(s*Bc)*H3c;
    #pragma unroll
    for (int q=0;q<3;q++){
      if (tBL[q] >= 0){
        const float* gp = gxb + (size_t)(b0+tBL[q])*H3c;
        int t = tT[q];
        gxr[q] = gp[t]; gxz[q] = gp[Hc+t]; gxn[q] = gp[2*Hc+t];
      }
    }
    floatx4 acc[4] = {{0.f,0.f,0.f,0.f},{0.f,0.f,0.f,0.f},{0.f,0.f,0.f,0.f},{0.f,0.f,0.f,0.f}};
    const u16* bBase = bF + (size_t)n16*40 + (size_t)quad*8;
    #pragma unroll
    for (int c=0;c<10;c++){
      short8 b8 = *(const short8*)(bBase + (size_t)c*640);
      int ca = (c<5)? c : (c-5);
      #pragma unroll
      for (int ti=0;ti<4;ti++)
        acc[ti] = __builtin_amdgcn_mfma_f32_16x16x32_bf16(whhA[ti][ca], b8, acc[ti], 0,0,0);
    }
    if (n16 < 8){
      #pragma unroll
      for (int ti=0;ti<4;ti++){
        int tile = w*4 + ti;
        if (tile < 30){
          int row0 = tile*16 + quad*4;
          float* gp = g_l + row0*10 + n16;
          #pragma unroll
          for (int r=0;r<4;r++) gp[r*10] = acc[ti][r];
        }
      }
    }
    __syncthreads();
    #pragma unroll
    for (int q=0;q<3;q++){
      if (tBL[q] >= 0){
        int t = tT[q], bl = tBL[q];
        float a_r = gxr[q] + g_l[t*10+bl] + bh_r[q];
        float a_z = gxz[q] + g_l[(160+t)*10+bl] + bh_z[q];
        float r  = 1.f/(1.f+__expf(-a_r));
        float zz = 1.f/(1.f+__expf(-a_z));
        float nx = gxn[q] + r*(g_l[(320+t)*10+bl] + bh_n[q]);
        nx = fminf(fmaxf(nx,-15.f),15.f);
        float e2 = __expf(2.f*nx);
        float n = (e2-1.f)/(e2+1.f);
        float h = (1.f-zz)*n + zz*hst[q];
        hst[q] = h;
        u16 hi = f2us(h); float hif = us2f(hi); u16 lo = f2us(h - hif);
        bF[(t>>5)*640 + bl*40 + (t&31)] = hi;
        bF[(5+(t>>5))*640 + bl*40 + (t&31)] = lo;
      }
    }
  }
  #pragma unroll
  for (int q=0;q<3;q++){
    if (tBL[q] >= 0)
      ws[OFF_HT + (size_t)(b0+tBL[q])*Hc + tT[q]] = hst[q];
  }
}

// ---------- z = mu + sigma * z_noise ----------
__global__ void z_kernel(const float* __restrict__ z_noise, const float* __restrict__ mu_w,
                         const float* __restrict__ mu_b, const float* __restrict__ std_w,
                         const float* __restrict__ std_b, float* __restrict__ ws){
  int o = blockIdx.x*256 + threadIdx.x;
  if (o >= Bc*Hc) return;
  int t = o % Hc, b = o / Hc;
  const float* h = ws + OFF_HT + b*Hc;
  const float2* mwr = (const float2*)(mu_w + t*Hc);
  const float2* swr = (const float2*)(std_w + t*Hc);
  float mu = mu_b[t], lv = std_b[t];
  for (int j=0;j<Hc/2;j++){
    float2 mw = mwr[j], sw = swr[j];
    float h0 = h[2*j], h1 = h[2*j+1];
    mu += h0*mw.x + h1*mw.y;
    lv += h0*sw.x + h1*sw.y;
  }
  float sg = expf(0.5f*lv);
  ws[OFF_Z + o] = mu + sg*z_noise[o];
}

// ---------- causes v6: 640 thr = 10 waves; wave w owns r/z/n tiles of row-stripe w ----------
// Gates fully in registers (C-layout); h in registers; bF ping-pong -> ONE barrier/step.
// grid 256 = 64 nets x 4 batch-groups of 8 (XCD affinity via kk%8... block = bg*64+kk).
__global__ void __launch_bounds__(640,3) causes4_kernel(
    const float* __restrict__ net_wih, const float* __restrict__ net_whh,
    const float* __restrict__ net_bih, const float* __restrict__ net_bhh,
    const float* __restrict__ ws, float* __restrict__ out){
  __shared__ __align__(16) u16 bF[2][14*16*40];   // ping-pong, 2 x 17.9 KB
  int kk = blockIdx.x & 63, bg = blockIdx.x >> 6, b0 = bg*8;
  int tid = threadIdx.x;
  int w = tid >> 6, lane = tid & 63, quad = lane >> 4, n16 = lane & 15;
  const float* whhk = net_whh + (size_t)kk*H3c*Hc;
  const float* wihk = net_wih + (size_t)kk*H3c*Wc;
  const float* bihk = net_bih + kk*H3c;
  const float* bhhk = net_bhh + kk*H3c;

  // ---- A-frags: A row = w*16 + n16 within each 150-row section ----
  int sr = w*16 + n16;
  bool rok = sr < Hc;
  short8 Ah[3][5], Ai[3][4];
  #pragma unroll
  for (int sec=0;sec<3;sec++){
    int grow = sec*Hc + sr;
    #pragma unroll
    for (int c=0;c<5;c++){
      union { short8 v; u16 u[8]; } t8;
      #pragma unroll
      for (int j=0;j<8;j++){
        int k = c*32 + quad*8 + j;
        t8.u[j] = f2us((rok && k < Hc) ? whhk[(size_t)grow*Hc + k] : 0.f);
      }
      Ah[sec][c] = t8.v;
    }
    #pragma unroll
    for (int c=0;c<4;c++){
      union { short8 v; u16 u[8]; } t8;
      #pragma unroll
      for (int j=0;j<8;j++){
        int k = c*32 + quad*8 + j;
        t8.u[j] = f2us((rok && k < Wc) ? wihk[(size_t)grow*Wc + k] : 0.f);
      }
      Ai[sec][c] = t8.v;
    }
  }

  // ---- per-lane C rows: t = t0+r (r=0..3), col bb=n16 ----
  int t0 = w*16 + quad*4;
  float bR[4], bZ[4], bNh[4], bNp[4], hst[4];
  #pragma unroll
  for (int r=0;r<4;r++){
    int t = t0 + r;
    bool v = (t < Hc) && (n16 < 8);
    bR[r]  = v ? (bhhk[t] + bihk[t]) : 0.f;
    bZ[r]  = v ? (bhhk[Hc+t] + bihk[Hc+t]) : 0.f;
    bNh[r] = v ? bhhk[2*Hc+t] : 0.f;
    bNp[r] = v ? bihk[2*Hc+t] : 0.f;
    hst[r] = v ? ws[OFF_Z + (size_t)(b0+n16)*Hc + t] : 0.f;
  }

  // ---- zero both buffers, then stage h0 + x0 into buf 0 ----
  for (int i=tid; i<2*14*16*40/2; i+=640) ((u32*)bF)[i] = 0u;
  __syncthreads();
  if (n16 < 8){
    #pragma unroll
    for (int p=0;p<2;p++){
      int t = t0 + p*2;
      u16 h0 = f2us(hst[p*2]);   u16 l0 = f2us(hst[p*2]   - us2f(h0));
      u16 h1 = f2us(hst[p*2+1]); u16 l1 = f2us(hst[p*2+1] - us2f(h1));
      *(u32*)&bF[0][(t>>5)*640     + n16*40 + (t&31)] = (u32)h0 | ((u32)h1<<16);
      *(u32*)&bF[0][(5+(t>>5))*640 + n16*40 + (t&31)] = (u32)l0 | ((u32)l1<<16);
    }
  }
  for (int it=tid; it<800; it+=640){
    int bb = it/100, i = it - bb*100;
    bF[0][(10+(i>>5))*640 + bb*40 + (i&31)] = f2us(ws[OFF_WX + (size_t)(b0+bb)*KWc + i]);
  }

  for (int s=0;s<Kc;s++){
    __syncthreads();                    // wb's old reads done; rb's writes visible
    const u16* rb = bF[s&1];
    u16* wb = bF[(s+1)&1];
    // x(s+1) -> wb, overlaps MFMA
    if (s < Kc-1){
      for (int it=tid; it<800; it+=640){
        int bb = it/100, i = it - bb*100;
        wb[(10+(i>>5))*640 + bb*40 + (i&31)] = f2us(ws[OFF_WX + (size_t)(b0+bb)*KWc + (s+1)*Wc + i]);
      }
    }
    // MFMA: acc init = bias
    floatx4 aR  = {bR[0],bR[1],bR[2],bR[3]};
    floatx4 aZ  = {bZ[0],bZ[1],bZ[2],bZ[3]};
    floatx4 aNh = {bNh[0],bNh[1],bNh[2],bNh[3]};
    floatx4 aNp = {bNp[0],bNp[1],bNp[2],bNp[3]};
    const u16* base = rb + (size_t)n16*40 + (size_t)quad*8;
    #pragma unroll
    for (int c=0;c<14;c++){
      short8 b8 = *(const short8*)(base + (size_t)c*640);
      if (c < 10){
        int ca = (c<5)? c : (c-5);
        aR  = __builtin_amdgcn_mfma_f32_16x16x32_bf16(Ah[0][ca], b8, aR, 0,0,0);
        aZ  = __builtin_amdgcn_mfma_f32_16x16x32_bf16(Ah[1][ca], b8, aZ, 0,0,0);
        aNh = __builtin_amdgcn_mfma_f32_16x16x32_bf16(Ah[2][ca], b8, aNh,0,0,0);
      } else {
        int ca = c-10;
        aR  = __builtin_amdgcn_mfma_f32_16x16x32_bf16(Ai[0][ca], b8, aR, 0,0,0);
        aZ  = __builtin_amdgcn_mfma_f32_16x16x32_bf16(Ai[1][ca], b8, aZ, 0,0,0);
        aNp = __builtin_amdgcn_mfma_f32_16x16x32_bf16(Ai[2][ca], b8, aNp,0,0,0);
      }
    }
    // gates in registers
    #pragma unroll
    for (int r=0;r<4;r++){
      bool v = (t0 + r < Hc) && (n16 < 8);
      float rr = 1.f/(1.f+__expf(-aR[r]));
      float zz = 1.f/(1.f+__expf(-aZ[r]));
      float nx = aNp[r] + rr*aNh[r];
      nx = fminf(fmaxf(nx,-15.f),15.f);
      float e2 = __expf(2.f*nx);
      float n = (e2-1.f)/(e2+1.f);
      float h = (1.f-zz)*n + zz*hst[r];
      hst[r] = v ? h : 0.f;
    }
    // h(s+1) -> wb (packed pairs)
    if (n16 < 8){
      #pragma unroll
      for (int p=0;p<2;p++){
        int t = t0 + p*2;
        u16 h0 = f2us(hst[p*2]);   u16 l0 = f2us(hst[p*2]   - us2f(h0));
        u16 h1 = f2us(hst[p*2+1]); u16 l1 = f2us(hst[p*2+1] - us2f(h1));
        *(u32*)&wb[(t>>5)*640     + n16*40 + (t&31)] = (u32)h0 | ((u32)h1<<16);
        *(u32*)&wb[(5+(t>>5))*640 + n16*40 + (t&31)] = (u32)l0 | ((u32)l1<<16);
      }
    }
  }
  if (n16 < 8){
    #pragma unroll
    for (int r=0;r<4;r++){
      int t = t0 + r;
      if (t < Hc)
        out[((size_t)(b0+n16)*Kc + kk)*Hc + t] = hst[r];
    }
  }
}

extern "C" void kernel_launch(void* const* d_in, const int* in_sizes, int n_in,
                              void* d_out, int out_size, void* d_ws, size_t ws_size,
                              hipStream_t stream){
  const float* x        = (const float*)d_in[0];
  const float* y        = (const float*)d_in[1];
  const float* z_noise  = (const float*)d_in[2];
  const float* lin_w    = (const float*)d_in[3];
  const float* lin_b    = (const float*)d_in[4];
  const float* a        = (const float*)d_in[5];
  const float* bias     = (const float*)d_in[6];
  const float* gl_wih   = (const float*)d_in[7];
  const float* gl_whh   = (const float*)d_in[8];
  const float* gl_bih   = (const float*)d_in[9];
  const float* gl_bhh   = (const float*)d_in[10];
  const float* mu_w     = (const float*)d_in[11];
  const float* mu_b     = (const float*)d_in[12];
  const float* std_w    = (const float*)d_in[13];
  const float* std_b    = (const float*)d_in[14];
  const float* net_wih  = (const float*)d_in[15];
  const float* net_whh  = (const float*)d_in[16];
  const float* net_bih  = (const float*)d_in[17];
  const float* net_bhh  = (const float*)d_in[18];
  float* ws = (float*)d_ws;
  float* out = (float*)d_out;

  wx_kernel<<<(Bc*KWc+255)/256, 256, 0, stream>>>(x, lin_w, lin_b, ws);
  attn_kernel<<<Bc*Kc, 256, 0, stream>>>(y, a, bias, ws);
  glproj_kernel<<<(Kc*Bc*H3c+255)/256, 256, 0, stream>>>(gl_wih, gl_bih, ws);
  glgru4_kernel<<<4, 512, 0, stream>>>(gl_whh, gl_bhh, ws);
  z_kernel<<<(Bc*Hc+255)/256, 256, 0, stream>>>(z_noise, mu_w, mu_b, std_w, std_b, ws);
  causes4_kernel<<<Kc*4, 640, 0, stream>>>(net_wih, net_whh, net_bih, net_bhh, ws, out);
}